// Round 25
// baseline (3561.585 us; speedup 1.0000x reference)
//
#include <hip/hip_runtime.h>

#define NQ 273

typedef float f4 __attribute__((ext_vector_type(4)));
typedef float f2 __attribute__((ext_vector_type(2)));
typedef _Float16 hf2 __attribute__((ext_vector_type(2)));

// ---------------- compile-time GA tables (Cl(3,0,1) PGA, 16 blades) ----------------
struct GATab {
  int qi[NQ]; int qj[NQ]; int qk[NQ];
  float qs[NQ];
  int qgp[NQ];
  int qpath[NQ];
  int qnew[NQ];   // 1 if this term's coef index differs from previous (after sort)
  int ngp, njp, nq;
};

constexpr int popc4(int m){ int c=0; for(int b=0;b<5;++b) c+=(m>>b)&1; return c; }
constexpr int swap_par(int a,int b){ int s=0; a>>=1; while(a){ s+=popc4(a&b); a>>=1; } return s&1; }

constexpr GATab make_tab(){
  GATab t{};
  int bladeOf[16]={}; int idxOf[16]={};
  { int p=0;
    for(int g=0; g<=4; ++g)
      for(int m=0; m<16; ++m)
        if(popc4(m)==g){ bladeOf[p]=m; idxOf[m]=p; ++p; }
  }
  int grade[16]={};
  for(int j=0;j<16;++j) grade[j]=popc4(bladeOf[j]);
  bool gpp[125]={}; bool jpp[125]={};
  for(int j=0;j<16;++j) for(int k=0;k<16;++k){
    int mj=bladeOf[j], mk=bladeOf[k];
    if(!(mj&mk&1)){ int i=idxOf[mj^mk]; gpp[(grade[i]*5+grade[j])*5+grade[k]]=true; }
    int cj=15^mj, ck=15^mk;
    if(!(cj&ck)){ int r=mj&mk; int i=idxOf[r]; jpp[(grade[i]*5+grade[j])*5+grade[k]]=true; }
  }
  int gpidx[125]={}; int jpidx[125]={};
  { int c=0; for(int u=0;u<125;++u){ gpidx[u] = gpp[u]? c++ : -1; } t.ngp=c; }
  { int c=0; for(int u=0;u<125;++u){ jpidx[u] = jpp[u]? c++ : -1; } t.njp=c; }
  int q=0;
  for(int j=0;j<16;++j) for(int k=0;k<16;++k){
    int mj=bladeOf[j], mk=bladeOf[k];
    if(!(mj&mk&1)){
      int i=idxOf[mj^mk];
      t.qi[q]=i; t.qj[q]=j; t.qk[q]=k;
      t.qs[q] = swap_par(mj,mk) ? -1.0f : 1.0f;
      t.qgp[q]=1;
      t.qpath[q]=gpidx[(grade[i]*5+grade[j])*5+grade[k]];
      ++q;
    }
  }
  for(int j=0;j<16;++j) for(int k=0;k<16;++k){
    int mj=bladeOf[j], mk=bladeOf[k];
    int cj=15^mj, ck=15^mk;
    if(!(cj&ck)){
      int r=mj&mk; int i=idxOf[r];
      int par = swap_par(mj,15^mj) ^ swap_par(mk,15^mk) ^ swap_par(cj,ck) ^ swap_par(r,15^r);
      t.qi[q]=i; t.qj[q]=j; t.qk[q]=k;
      t.qs[q] = par ? -1.0f : 1.0f;
      t.qgp[q]=0;
      t.qpath[q]=jpidx[(grade[i]*5+grade[j])*5+grade[k]];
      ++q;
    }
  }
  t.nq=q;

  // sort terms by coef index (gp paths first, then jp) so terms sharing one
  // coef value are adjacent -> ONE rolling-register LDS read per unique coef.
  for(int a=1;a<t.nq;++a){
    int ci=t.qi[a], cj2=t.qj[a], ck2=t.qk[a], cg=t.qgp[a], cp=t.qpath[a]; float cs=t.qs[a];
    int key = cg ? cp : 1000+cp;
    int b=a-1;
    while(b>=0){
      int kb = t.qgp[b] ? t.qpath[b] : 1000+t.qpath[b];
      if(kb <= key) break;
      t.qi[b+1]=t.qi[b]; t.qj[b+1]=t.qj[b]; t.qk[b+1]=t.qk[b];
      t.qs[b+1]=t.qs[b]; t.qgp[b+1]=t.qgp[b]; t.qpath[b+1]=t.qpath[b];
      --b;
    }
    t.qi[b+1]=ci; t.qj[b+1]=cj2; t.qk[b+1]=ck2; t.qs[b+1]=cs; t.qgp[b+1]=cg; t.qpath[b+1]=cp;
  }
  for(int a=0;a<t.nq;++a){
    if(a==0){ t.qnew[a]=1; continue; }
    int ka = t.qgp[a]   ? t.qpath[a]   : 1000+t.qpath[a];
    int kb = t.qgp[a-1] ? t.qpath[a-1] : 1000+t.qpath[a-1];
    t.qnew[a] = (ka!=kb) ? 1 : 0;
  }
  return t;
}

constexpr GATab TAB = make_tab();
static_assert(TAB.nq == NQ, "nonzero count mismatch");
static_assert(TAB.ngp > 0 && TAB.njp > 0, "path counts");
constexpr int NGPC = TAB.ngp;
constexpr int NJPC = TAB.njp;
constexpr int GR[16] = {0,1,1,1,1,2,2,2,2,2,2,3,3,3,3,4};

// compact coef tables (fp16 in LDS): odd-padded rows -> per-lane stride odd
// (u16 units) -> spread banks, <=2-way aliasing (free, m136).
constexpr int PADG = (NGPC & 1) ? NGPC : NGPC + 1;
constexpr int PADJ = (NJPC & 1) ? NJPC : NJPC + 1;
constexpr int CGF  = 64 * PADG;          // u16 count (gp)
constexpr int CJF  = 64 * PADJ;          // u16 count (jp)
constexpr int XLF  = 4 * 64 * 16;        // x staging: 4 waves x (64 i x 16 v) floats = 16 KB
static_assert(((CGF + CJF) & 1) == 0, "u32-copy needs even u16 count");
static_assert((CGF + CJF) * 2 + XLF * 4 <= 22 * 1024 + 768, "7 blocks/CU check");

// ---------------- prep kernels ----------------
// fp16 weight table (R18/R23/R24-proven): wrph[(i*5+s)*64+n] = h(w1[s]) | h(w2[s])<<16
__global__ void prep_wrph(const float* __restrict__ linw, unsigned* __restrict__ wrph){
  int t = blockIdx.x*blockDim.x + threadIdx.x;
  if(t < 64*5*64){
    int n = t & 63;
    int s = (t >> 6) % 5;
    int i = t / 320;
    float w1 = linw[(n*64 + i)*5 + s];
    float w2 = linw[((64+n)*64 + i)*5 + s];
    unsigned short a = __builtin_bit_cast(unsigned short, (_Float16)w1);
    unsigned short b = __builtin_bit_cast(unsigned short, (_Float16)w2);
    wrph[t] = (unsigned)a | ((unsigned)b << 16);
  }
}

// coef tables as fp16 u16: cgh[n*PADG+p] (gp), cgh[CGF + n*PADJ+p] (jp)
__global__ void prep_cph(const float* __restrict__ gpw, const float* __restrict__ jpw,
                         unsigned short* __restrict__ cgh){
  int n = threadIdx.x; // blockDim = 64, grid = 1
  for(int p=0;p<NGPC;++p)
    cgh[n*PADG + p] = __builtin_bit_cast(unsigned short, (_Float16)gpw[n*NGPC + p]);
  for(int p=0;p<NJPC;++p)
    cgh[CGF + n*PADJ + p] = __builtin_bit_cast(unsigned short, (_Float16)jpw[n*NJPC + p]);
}

// ---------------- main fused kernel ----------------
// R24 (PASSED 477us) + ONE change: coef table fp16 in LDS -> LDS/block
// 28.5 -> ~22.4 KB -> 7 blocks/CU (was 5), +40% nominal waves. The kernel is
// latency-bound (R24: VALU/DS/L1 each ~130-200us but dur 505; occupancy 36%),
// so waves are the lever. Coef cvt cost: 1 per UNIQUE coef (~68/elem, noise).
// R22's failure re-audited: __shared__ u16 array has 2-B natural alignment;
// u32 staging writes through a cast pointer were potentially misaligned ->
// garbage coefs. Fix: declare storage as u32 (cl32, 4-B aligned base), read
// u16 halves via cast. Everything else byte-identical to R24:
//  - fp16 pair weights + packed-fp32 linear (v_pk_fma_f32, op_sel splats)
//  - x prefetch rotation (HBM latency under linear phase)
//  - sorted rolling-coef bilinear + sched_barrier(0x7) anti-hoist
//  - swizzled b128 staging, broadcast f4 reads (0 conflicts)
__global__ __launch_bounds__(256)
void main_k(const float* __restrict__ x, const unsigned short* __restrict__ cgh,
            const unsigned* __restrict__ wrph, float* __restrict__ out, int B){
  __shared__ unsigned cl32[(CGF + CJF)/2];   // u32 storage -> 4-B aligned base
  __shared__ float xl[XLF];

  const int tid  = threadIdx.x;
  const int lane = tid & 63;
  const int wv   = tid >> 6;        // 0..3
  const int n    = lane;

  // ---- stage fp16 coef tables once per block (aligned u32 copies) ----
  {
    const unsigned* src = (const unsigned*)cgh;
    for(int idx = tid; idx < (CGF + CJF)/2; idx += 256) cl32[idx] = src[idx];
  }
  __syncthreads();
  const unsigned short* cl16 = (const unsigned short*)cl32;

  const int cgbase = n*PADG;
  const int cjbase = CGF + n*PADJ;
  float* xw = xl + wv*1024;        // this wave's 64 i x 16 v staging region
  const int stride = gridDim.x*4;

  // ---- prologue: load + stage first element ----
  int bb = blockIdx.x*4 + wv;
  if(bb < B){
    const f4* src = (const f4*)(x + ((long)bb*64 + lane)*16);
    #pragma unroll
    for(int r=0;r<4;++r){
      f4 a = __builtin_nontemporal_load(src+r);
      int daddr = (lane*16 + r*4) ^ ((lane&7)<<2);
      *(f4*)(xw + daddr) = a;
    }
  }

  for(; bb < B; bb += stride){
    const int nb = bb + stride;

    // ---- issue NEXT element's loads now (HBM latency hides under linear) ----
    f4 xn[4];
    if(nb < B){
      const f4* src = (const f4*)(x + ((long)nb*64 + lane)*16);
      #pragma unroll
      for(int r=0;r<4;++r) xn[r] = __builtin_nontemporal_load(src+r);
    }

    // ---- linear phase (packed): y12[v] = sum_i (w1,w2)[g(v)] * (xv,xv) ----
    f2 y12[16];
    #pragma unroll
    for(int v=0;v<16;++v) y12[v] = (f2)(0.f);

    #pragma unroll 4
    for(int i=0;i<64;++i){
      const unsigned* wp = wrph + i*320 + n;
      unsigned u0 = wp[0], u1 = wp[64], u2 = wp[128], u3 = wp[192], u4 = wp[256];
      f2 w12[5];
      { hf2 h = __builtin_bit_cast(hf2, u0); w12[0][0]=(float)h[0]; w12[0][1]=(float)h[1]; }
      { hf2 h = __builtin_bit_cast(hf2, u1); w12[1][0]=(float)h[0]; w12[1][1]=(float)h[1]; }
      { hf2 h = __builtin_bit_cast(hf2, u2); w12[2][0]=(float)h[0]; w12[2][1]=(float)h[1]; }
      { hf2 h = __builtin_bit_cast(hf2, u3); w12[3][0]=(float)h[0]; w12[3][1]=(float)h[1]; }
      { hf2 h = __builtin_bit_cast(hf2, u4); w12[4][0]=(float)h[0]; w12[4][1]=(float)h[1]; }

      // broadcast reads of x (uniform addr, conflict-free); splats (x_c,x_c)
      // with literal lane indices -> fold into VOP3P op_sel
      #pragma unroll
      for(int g=0;g<4;++g){
        int raddr = (i*16 + g*4) ^ ((i&7)<<2);
        f4 a = *(const f4*)(xw + raddr);
        f2 p0 = __builtin_shufflevector(a, a, 0,0);
        f2 p1 = __builtin_shufflevector(a, a, 1,1);
        f2 p2 = __builtin_shufflevector(a, a, 2,2);
        f2 p3 = __builtin_shufflevector(a, a, 3,3);
        y12[g*4+0] = __builtin_elementwise_fma(w12[GR[g*4+0]], p0, y12[g*4+0]);
        y12[g*4+1] = __builtin_elementwise_fma(w12[GR[g*4+1]], p1, y12[g*4+1]);
        y12[g*4+2] = __builtin_elementwise_fma(w12[GR[g*4+2]], p2, y12[g*4+2]);
        y12[g*4+3] = __builtin_elementwise_fma(w12[GR[g*4+3]], p3, y12[g*4+3]);
      }
    }

    // ---- stage NEXT element into the (now fully-read) buffer ----
    if(nb < B){
      #pragma unroll
      for(int r=0;r<4;++r){
        int daddr = (lane*16 + r*4) ^ ((lane&7)<<2);
        *(f4*)(xw + daddr) = xn[r];
      }
    }

    // ---- bilinear phase: sorted terms, rolling coef register, capped hoist ----
    __builtin_amdgcn_sched_barrier(0x7);
    float acc[16];
    #pragma unroll
    for(int v=0;v<16;++v) acc[v] = y12[v][1];   // + y2

    float c = 0.f;
    #pragma unroll
    for(int q=0;q<NQ;++q){
      if(TAB.qnew[q]){
        unsigned short raw = TAB.qgp[q] ? cl16[cgbase + TAB.qpath[q]]
                                        : cl16[cjbase + TAB.qpath[q]];
        c = (float)__builtin_bit_cast(_Float16, raw);
      }
      float prod = y12[TAB.qj[q]][0] * y12[TAB.qk[q]][1];
      acc[TAB.qi[q]] = fmaf((TAB.qs[q] < 0.f) ? -c : c, prod, acc[TAB.qi[q]]);
      if((q % 24) == 23) __builtin_amdgcn_sched_barrier(0x7);
    }
    __builtin_amdgcn_sched_barrier(0x7);

    // ---- store (streamed once -> nontemporal) ----
    {
      f4* op = (f4*)(out + ((long)bb*64 + n)*16);
      #pragma unroll
      for(int r=0;r<4;++r){
        f4 o; o[0]=acc[4*r]; o[1]=acc[4*r+1]; o[2]=acc[4*r+2]; o[3]=acc[4*r+3];
        __builtin_nontemporal_store(o, op+r);
      }
    }
  }
}

extern "C" void kernel_launch(void* const* d_in, const int* in_sizes, int n_in,
                              void* d_out, int out_size, void* d_ws, size_t ws_size,
                              hipStream_t stream){
  const float* x    = (const float*)d_in[0];
  const float* gpw  = (const float*)d_in[1];
  const float* jpw  = (const float*)d_in[2];
  const float* linw = (const float*)d_in[3];
  float* outp = (float*)d_out;

  unsigned* wrph = (unsigned*)d_ws;                       // 64*5*64 u32 = 80 KB
  unsigned short* cgh = (unsigned short*)(wrph + 64*5*64); // (CGF+CJF) u16 ~ 6.4 KB

  int B = in_sizes[0] / (64*16);

  prep_wrph<<<80, 256, 0, stream>>>(linw, wrph);
  prep_cph <<<1,  64,  0, stream>>>(gpw, jpw, cgh);
  main_k   <<<1792, 256, 0, stream>>>(x, cgh, wrph, outp, B);
}

// Round 26
// 463.793 us; speedup vs baseline: 7.6793x; 7.6793x over previous
//
#include <hip/hip_runtime.h>

#define NQ 273

typedef float f4 __attribute__((ext_vector_type(4)));
typedef float f2 __attribute__((ext_vector_type(2)));
typedef _Float16 hf2 __attribute__((ext_vector_type(2)));

// ---------------- compile-time GA tables (Cl(3,0,1) PGA, 16 blades) ----------------
struct GATab {
  int qi[NQ]; int qj[NQ]; int qk[NQ];
  float qs[NQ];
  int qgp[NQ];
  int qpath[NQ];
  int qnew[NQ];   // 1 if this term's coef index differs from previous (after sort)
  int ngp, njp, nq;
};

constexpr int popc4(int m){ int c=0; for(int b=0;b<5;++b) c+=(m>>b)&1; return c; }
constexpr int swap_par(int a,int b){ int s=0; a>>=1; while(a){ s+=popc4(a&b); a>>=1; } return s&1; }

constexpr GATab make_tab(){
  GATab t{};
  int bladeOf[16]={}; int idxOf[16]={};
  { int p=0;
    for(int g=0; g<=4; ++g)
      for(int m=0; m<16; ++m)
        if(popc4(m)==g){ bladeOf[p]=m; idxOf[m]=p; ++p; }
  }
  int grade[16]={};
  for(int j=0;j<16;++j) grade[j]=popc4(bladeOf[j]);
  bool gpp[125]={}; bool jpp[125]={};
  for(int j=0;j<16;++j) for(int k=0;k<16;++k){
    int mj=bladeOf[j], mk=bladeOf[k];
    if(!(mj&mk&1)){ int i=idxOf[mj^mk]; gpp[(grade[i]*5+grade[j])*5+grade[k]]=true; }
    int cj=15^mj, ck=15^mk;
    if(!(cj&ck)){ int r=mj&mk; int i=idxOf[r]; jpp[(grade[i]*5+grade[j])*5+grade[k]]=true; }
  }
  int gpidx[125]={}; int jpidx[125]={};
  { int c=0; for(int u=0;u<125;++u){ gpidx[u] = gpp[u]? c++ : -1; } t.ngp=c; }
  { int c=0; for(int u=0;u<125;++u){ jpidx[u] = jpp[u]? c++ : -1; } t.njp=c; }
  int q=0;
  for(int j=0;j<16;++j) for(int k=0;k<16;++k){
    int mj=bladeOf[j], mk=bladeOf[k];
    if(!(mj&mk&1)){
      int i=idxOf[mj^mk];
      t.qi[q]=i; t.qj[q]=j; t.qk[q]=k;
      t.qs[q] = swap_par(mj,mk) ? -1.0f : 1.0f;
      t.qgp[q]=1;
      t.qpath[q]=gpidx[(grade[i]*5+grade[j])*5+grade[k]];
      ++q;
    }
  }
  for(int j=0;j<16;++j) for(int k=0;k<16;++k){
    int mj=bladeOf[j], mk=bladeOf[k];
    int cj=15^mj, ck=15^mk;
    if(!(cj&ck)){
      int r=mj&mk; int i=idxOf[r];
      int par = swap_par(mj,15^mj) ^ swap_par(mk,15^mk) ^ swap_par(cj,ck) ^ swap_par(r,15^r);
      t.qi[q]=i; t.qj[q]=j; t.qk[q]=k;
      t.qs[q] = par ? -1.0f : 1.0f;
      t.qgp[q]=0;
      t.qpath[q]=jpidx[(grade[i]*5+grade[j])*5+grade[k]];
      ++q;
    }
  }
  t.nq=q;

  // sort terms by coef index (gp paths first, then jp) so terms sharing one
  // coef value are adjacent -> ONE rolling-register LDS read per unique coef.
  for(int a=1;a<t.nq;++a){
    int ci=t.qi[a], cj2=t.qj[a], ck2=t.qk[a], cg=t.qgp[a], cp=t.qpath[a]; float cs=t.qs[a];
    int key = cg ? cp : 1000+cp;
    int b=a-1;
    while(b>=0){
      int kb = t.qgp[b] ? t.qpath[b] : 1000+t.qpath[b];
      if(kb <= key) break;
      t.qi[b+1]=t.qi[b]; t.qj[b+1]=t.qj[b]; t.qk[b+1]=t.qk[b];
      t.qs[b+1]=t.qs[b]; t.qgp[b+1]=t.qgp[b]; t.qpath[b+1]=t.qpath[b];
      --b;
    }
    t.qi[b+1]=ci; t.qj[b+1]=cj2; t.qk[b+1]=ck2; t.qs[b+1]=cs; t.qgp[b+1]=cg; t.qpath[b+1]=cp;
  }
  for(int a=0;a<t.nq;++a){
    if(a==0){ t.qnew[a]=1; continue; }
    int ka = t.qgp[a]   ? t.qpath[a]   : 1000+t.qpath[a];
    int kb = t.qgp[a-1] ? t.qpath[a-1] : 1000+t.qpath[a-1];
    t.qnew[a] = (ka!=kb) ? 1 : 0;
  }
  return t;
}

constexpr GATab TAB = make_tab();
static_assert(TAB.nq == NQ, "nonzero count mismatch");
static_assert(TAB.ngp > 0 && TAB.njp > 0, "path counts");
constexpr int NGPC = TAB.ngp;
constexpr int NJPC = TAB.njp;
constexpr int GR[16] = {0,1,1,1,1,2,2,2,2,2,2,3,3,3,3,4};

// compact coef tables (fp32 in LDS, R21/R23/R24-proven): odd-padded rows ->
// per-lane stride odd (dwords) -> 2-way bank aliasing only (free, m136).
constexpr int PADG = (NGPC & 1) ? NGPC : NGPC + 1;
constexpr int PADJ = (NJPC & 1) ? NJPC : NJPC + 1;
constexpr int CGF  = 64 * PADG;          // floats
constexpr int CJF  = 64 * PADJ;          // floats
constexpr int XLF  = 8 * 64 * 16;        // x staging: 8 waves x (64 i x 16 v) = 32 KB
static_assert((CGF + CJF + XLF) * 4 <= 53 * 1024 + 512, "3 blocks/CU check (<=53.3KB)");

// ---------------- prep kernels ----------------
// fp16 weight table (R18/R23/R24-proven): wrph[(i*5+s)*64+n] = h(w1[s]) | h(w2[s])<<16
__global__ void prep_wrph(const float* __restrict__ linw, unsigned* __restrict__ wrph){
  int t = blockIdx.x*blockDim.x + threadIdx.x;
  if(t < 64*5*64){
    int n = t & 63;
    int s = (t >> 6) % 5;
    int i = t / 320;
    float w1 = linw[(n*64 + i)*5 + s];
    float w2 = linw[((64+n)*64 + i)*5 + s];
    unsigned short a = __builtin_bit_cast(unsigned short, (_Float16)w1);
    unsigned short b = __builtin_bit_cast(unsigned short, (_Float16)w2);
    wrph[t] = (unsigned)a | ((unsigned)b << 16);
  }
}

// pack gpw/jpw raw (fp32) into odd-padded rows
__global__ void prep_cpk(const float* __restrict__ gpw, const float* __restrict__ jpw,
                         float* __restrict__ cgj){
  int n = threadIdx.x; // blockDim = 64, grid = 1
  for(int p=0;p<NGPC;++p) cgj[n*PADG + p] = gpw[n*NGPC + p];
  for(int p=0;p<NJPC;++p) cgj[CGF + n*PADJ + p] = jpw[n*NJPC + p];
}

// ---------------- main fused kernel ----------------
// R24 (PASSED 477us, best) with ONE variable changed: 256 -> 512 threads,
// identical per-wave structure. Rationale: R24 is latency-bound with
// VGPR=64 (8-wave/SIMD register tier!) and zero conflicts/spill; the ONLY
// occupancy limiter is LDS blocks/CU (28.5KB -> 5 blocks x 4 waves = 20
// waves/CU). At 512-thr: 44.5KB -> 3 blocks x 8 waves = 24 waves/CU (+20%),
// coef staged once per 8 waves. The historical 512-thr hazard (128-VGPR
// clamp -> spill) does NOT apply at a 64-VGPR live set. (R25's fp16-coef
// attempt is dead: +72 VGPR and 6.4M u16-stride bank conflicts.)
// Frozen from R24: fp16 pair weights + packed-fp32 linear (v_pk_fma_f32,
// op_sel splats), x prefetch rotation, coef fp32 in LDS + sorted
// rolling-coef + sched_barrier(0x7), swizzled b128 staging / broadcast reads.
__global__ __launch_bounds__(512)
void main_k(const float* __restrict__ x, const float* __restrict__ cgj,
            const unsigned* __restrict__ wrph, float* __restrict__ out, int B){
  __shared__ float lds[CGF + CJF + XLF];
  float* clg = lds;
  float* clj = lds + CGF;
  float* xl  = lds + CGF + CJF;

  const int tid  = threadIdx.x;
  const int lane = tid & 63;
  const int wv   = tid >> 6;        // 0..7
  const int n    = lane;

  // ---- stage coef tables once per block ----
  for(int idx = tid; idx < CGF + CJF; idx += 512) lds[idx] = cgj[idx];
  __syncthreads();

  const int cgbase = n*PADG;
  const int cjbase = n*PADJ;
  float* xw = xl + wv*1024;        // this wave's 64 i x 16 v staging region
  const int stride = gridDim.x*8;

  // ---- prologue: load + stage first element ----
  int bb = blockIdx.x*8 + wv;
  if(bb < B){
    const f4* src = (const f4*)(x + ((long)bb*64 + lane)*16);
    #pragma unroll
    for(int r=0;r<4;++r){
      f4 a = __builtin_nontemporal_load(src+r);
      int daddr = (lane*16 + r*4) ^ ((lane&7)<<2);
      *(f4*)(xw + daddr) = a;
    }
  }

  for(; bb < B; bb += stride){
    const int nb = bb + stride;

    // ---- issue NEXT element's loads now (HBM latency hides under linear) ----
    f4 xn[4];
    if(nb < B){
      const f4* src = (const f4*)(x + ((long)nb*64 + lane)*16);
      #pragma unroll
      for(int r=0;r<4;++r) xn[r] = __builtin_nontemporal_load(src+r);
    }

    // ---- linear phase (packed): y12[v] = sum_i (w1,w2)[g(v)] * (xv,xv) ----
    f2 y12[16];
    #pragma unroll
    for(int v=0;v<16;++v) y12[v] = (f2)(0.f);

    #pragma unroll 4
    for(int i=0;i<64;++i){
      const unsigned* wp = wrph + i*320 + n;
      unsigned u0 = wp[0], u1 = wp[64], u2 = wp[128], u3 = wp[192], u4 = wp[256];
      f2 w12[5];
      { hf2 h = __builtin_bit_cast(hf2, u0); w12[0][0]=(float)h[0]; w12[0][1]=(float)h[1]; }
      { hf2 h = __builtin_bit_cast(hf2, u1); w12[1][0]=(float)h[0]; w12[1][1]=(float)h[1]; }
      { hf2 h = __builtin_bit_cast(hf2, u2); w12[2][0]=(float)h[0]; w12[2][1]=(float)h[1]; }
      { hf2 h = __builtin_bit_cast(hf2, u3); w12[3][0]=(float)h[0]; w12[3][1]=(float)h[1]; }
      { hf2 h = __builtin_bit_cast(hf2, u4); w12[4][0]=(float)h[0]; w12[4][1]=(float)h[1]; }

      // broadcast reads of x (uniform addr, conflict-free); splats (x_c,x_c)
      // with literal lane indices -> fold into VOP3P op_sel
      #pragma unroll
      for(int g=0;g<4;++g){
        int raddr = (i*16 + g*4) ^ ((i&7)<<2);
        f4 a = *(const f4*)(xw + raddr);
        f2 p0 = __builtin_shufflevector(a, a, 0,0);
        f2 p1 = __builtin_shufflevector(a, a, 1,1);
        f2 p2 = __builtin_shufflevector(a, a, 2,2);
        f2 p3 = __builtin_shufflevector(a, a, 3,3);
        y12[g*4+0] = __builtin_elementwise_fma(w12[GR[g*4+0]], p0, y12[g*4+0]);
        y12[g*4+1] = __builtin_elementwise_fma(w12[GR[g*4+1]], p1, y12[g*4+1]);
        y12[g*4+2] = __builtin_elementwise_fma(w12[GR[g*4+2]], p2, y12[g*4+2]);
        y12[g*4+3] = __builtin_elementwise_fma(w12[GR[g*4+3]], p3, y12[g*4+3]);
      }
    }

    // ---- stage NEXT element into the (now fully-read) buffer ----
    if(nb < B){
      #pragma unroll
      for(int r=0;r<4;++r){
        int daddr = (lane*16 + r*4) ^ ((lane&7)<<2);
        *(f4*)(xw + daddr) = xn[r];
      }
    }

    // ---- bilinear phase: sorted terms, rolling coef register, capped hoist ----
    __builtin_amdgcn_sched_barrier(0x7);
    float acc[16];
    #pragma unroll
    for(int v=0;v<16;++v) acc[v] = y12[v][1];   // + y2

    float c = 0.f;
    #pragma unroll
    for(int q=0;q<NQ;++q){
      if(TAB.qnew[q])
        c = TAB.qgp[q] ? clg[cgbase + TAB.qpath[q]] : clj[cjbase + TAB.qpath[q]];
      float prod = y12[TAB.qj[q]][0] * y12[TAB.qk[q]][1];
      acc[TAB.qi[q]] = fmaf((TAB.qs[q] < 0.f) ? -c : c, prod, acc[TAB.qi[q]]);
      if((q % 24) == 23) __builtin_amdgcn_sched_barrier(0x7);
    }
    __builtin_amdgcn_sched_barrier(0x7);

    // ---- store (streamed once -> nontemporal) ----
    {
      f4* op = (f4*)(out + ((long)bb*64 + n)*16);
      #pragma unroll
      for(int r=0;r<4;++r){
        f4 o; o[0]=acc[4*r]; o[1]=acc[4*r+1]; o[2]=acc[4*r+2]; o[3]=acc[4*r+3];
        __builtin_nontemporal_store(o, op+r);
      }
    }
  }
}

extern "C" void kernel_launch(void* const* d_in, const int* in_sizes, int n_in,
                              void* d_out, int out_size, void* d_ws, size_t ws_size,
                              hipStream_t stream){
  const float* x    = (const float*)d_in[0];
  const float* gpw  = (const float*)d_in[1];
  const float* jpw  = (const float*)d_in[2];
  const float* linw = (const float*)d_in[3];
  float* outp = (float*)d_out;

  unsigned* wrph = (unsigned*)d_ws;            // 64*5*64 u32 = 80 KB
  float*    cgj  = (float*)(wrph + 64*5*64);   // CGF+CJF floats (~12.5 KB)

  int B = in_sizes[0] / (64*16);

  prep_wrph<<<80, 256, 0, stream>>>(linw, wrph);
  prep_cpk <<<1,  64,  0, stream>>>(gpw, jpw, cgj);
  main_k   <<<768, 512, 0, stream>>>(x, cgj, wrph, outp, B);
}

// Round 27
// 445.937 us; speedup vs baseline: 7.9867x; 1.0400x over previous
//
#include <hip/hip_runtime.h>

#define NQ 273

typedef float f4 __attribute__((ext_vector_type(4)));
typedef float f2 __attribute__((ext_vector_type(2)));
typedef _Float16 hf2 __attribute__((ext_vector_type(2)));

// ---------------- compile-time GA tables (Cl(3,0,1) PGA, 16 blades) ----------------
struct GATab {
  int qi[NQ]; int qj[NQ]; int qk[NQ];
  float qs[NQ];
  int qgp[NQ];
  int qpath[NQ];
  int qnew[NQ];   // 1 if this term's coef index differs from previous (after sort)
  int ngp, njp, nq;
};

constexpr int popc4(int m){ int c=0; for(int b=0;b<5;++b) c+=(m>>b)&1; return c; }
constexpr int swap_par(int a,int b){ int s=0; a>>=1; while(a){ s+=popc4(a&b); a>>=1; } return s&1; }

constexpr GATab make_tab(){
  GATab t{};
  int bladeOf[16]={}; int idxOf[16]={};
  { int p=0;
    for(int g=0; g<=4; ++g)
      for(int m=0; m<16; ++m)
        if(popc4(m)==g){ bladeOf[p]=m; idxOf[m]=p; ++p; }
  }
  int grade[16]={};
  for(int j=0;j<16;++j) grade[j]=popc4(bladeOf[j]);
  bool gpp[125]={}; bool jpp[125]={};
  for(int j=0;j<16;++j) for(int k=0;k<16;++k){
    int mj=bladeOf[j], mk=bladeOf[k];
    if(!(mj&mk&1)){ int i=idxOf[mj^mk]; gpp[(grade[i]*5+grade[j])*5+grade[k]]=true; }
    int cj=15^mj, ck=15^mk;
    if(!(cj&ck)){ int r=mj&mk; int i=idxOf[r]; jpp[(grade[i]*5+grade[j])*5+grade[k]]=true; }
  }
  int gpidx[125]={}; int jpidx[125]={};
  { int c=0; for(int u=0;u<125;++u){ gpidx[u] = gpp[u]? c++ : -1; } t.ngp=c; }
  { int c=0; for(int u=0;u<125;++u){ jpidx[u] = jpp[u]? c++ : -1; } t.njp=c; }
  int q=0;
  for(int j=0;j<16;++j) for(int k=0;k<16;++k){
    int mj=bladeOf[j], mk=bladeOf[k];
    if(!(mj&mk&1)){
      int i=idxOf[mj^mk];
      t.qi[q]=i; t.qj[q]=j; t.qk[q]=k;
      t.qs[q] = swap_par(mj,mk) ? -1.0f : 1.0f;
      t.qgp[q]=1;
      t.qpath[q]=gpidx[(grade[i]*5+grade[j])*5+grade[k]];
      ++q;
    }
  }
  for(int j=0;j<16;++j) for(int k=0;k<16;++k){
    int mj=bladeOf[j], mk=bladeOf[k];
    int cj=15^mj, ck=15^mk;
    if(!(cj&ck)){
      int r=mj&mk; int i=idxOf[r];
      int par = swap_par(mj,15^mj) ^ swap_par(mk,15^mk) ^ swap_par(cj,ck) ^ swap_par(r,15^r);
      t.qi[q]=i; t.qj[q]=j; t.qk[q]=k;
      t.qs[q] = par ? -1.0f : 1.0f;
      t.qgp[q]=0;
      t.qpath[q]=jpidx[(grade[i]*5+grade[j])*5+grade[k]];
      ++q;
    }
  }
  t.nq=q;

  // sort terms by coef index (gp paths first, then jp) so terms sharing one
  // coef value are adjacent -> ONE rolling-register LDS read per unique coef.
  for(int a=1;a<t.nq;++a){
    int ci=t.qi[a], cj2=t.qj[a], ck2=t.qk[a], cg=t.qgp[a], cp=t.qpath[a]; float cs=t.qs[a];
    int key = cg ? cp : 1000+cp;
    int b=a-1;
    while(b>=0){
      int kb = t.qgp[b] ? t.qpath[b] : 1000+t.qpath[b];
      if(kb <= key) break;
      t.qi[b+1]=t.qi[b]; t.qj[b+1]=t.qj[b]; t.qk[b+1]=t.qk[b];
      t.qs[b+1]=t.qs[b]; t.qgp[b+1]=t.qgp[b]; t.qpath[b+1]=t.qpath[b];
      --b;
    }
    t.qi[b+1]=ci; t.qj[b+1]=cj2; t.qk[b+1]=ck2; t.qs[b+1]=cs; t.qgp[b+1]=cg; t.qpath[b+1]=cp;
  }
  for(int a=0;a<t.nq;++a){
    if(a==0){ t.qnew[a]=1; continue; }
    int ka = t.qgp[a]   ? t.qpath[a]   : 1000+t.qpath[a];
    int kb = t.qgp[a-1] ? t.qpath[a-1] : 1000+t.qpath[a-1];
    t.qnew[a] = (ka!=kb) ? 1 : 0;
  }
  return t;
}

constexpr GATab TAB = make_tab();
static_assert(TAB.nq == NQ, "nonzero count mismatch");
static_assert(TAB.ngp > 0 && TAB.njp > 0, "path counts");
constexpr int NGPC = TAB.ngp;
constexpr int NJPC = TAB.njp;
constexpr int GR[16] = {0,1,1,1,1,2,2,2,2,2,2,3,3,3,3,4};

// compact coef tables (fp32 in LDS, proven): odd-padded rows -> per-lane
// stride odd (dwords) -> 2-way bank aliasing only (free, m136).
constexpr int PADG = (NGPC & 1) ? NGPC : NGPC + 1;
constexpr int PADJ = (NJPC & 1) ? NJPC : NJPC + 1;
constexpr int CGF  = 64 * PADG;          // floats
constexpr int CJF  = 64 * PADJ;          // floats
constexpr int XLF  = 8 * 64 * 16;        // x staging: 8 waves x (64 i x 16 v) = 32 KB
static_assert((CGF + CJF + XLF) * 4 <= 53 * 1024 + 512, "3 blocks/CU check (<=53.3KB)");

// ---------------- prep kernels ----------------
// fp16 weight table (R18/R23/R24/R26-proven): wrph[(i*5+s)*64+n] = h(w1[s]) | h(w2[s])<<16
__global__ void prep_wrph(const float* __restrict__ linw, unsigned* __restrict__ wrph){
  int t = blockIdx.x*blockDim.x + threadIdx.x;
  if(t < 64*5*64){
    int n = t & 63;
    int s = (t >> 6) % 5;
    int i = t / 320;
    float w1 = linw[(n*64 + i)*5 + s];
    float w2 = linw[((64+n)*64 + i)*5 + s];
    unsigned short a = __builtin_bit_cast(unsigned short, (_Float16)w1);
    unsigned short b = __builtin_bit_cast(unsigned short, (_Float16)w2);
    wrph[t] = (unsigned)a | ((unsigned)b << 16);
  }
}

// pack gpw/jpw raw (fp32) into odd-padded rows
__global__ void prep_cpk(const float* __restrict__ gpw, const float* __restrict__ jpw,
                         float* __restrict__ cgj){
  int n = threadIdx.x; // blockDim = 64, grid = 1
  for(int p=0;p<NGPC;++p) cgj[n*PADG + p] = gpw[n*NGPC + p];
  for(int p=0;p<NJPC;++p) cgj[CGF + n*PADJ + p] = jpw[n*NJPC + p];
}

// ---------------- main fused kernel ----------------
// R26 (PASSED 464us, best) with ONE variable changed: PLAIN stores instead of
// nontemporal. Theory: each global_store_dwordx4 writes 16 B/lane at 64-B
// stride -> one instruction touches 64 PARTIAL cache lines; the 4 stores
// (r=0..3) complete each line, but the NT hint defeats L2 write-combining ->
// partial sectors stream to HBM. That matches the constant 1.63x WRITE
// amplification (438 vs 268 MB ideal) seen in every spill-free variant.
// Plain stores let L2 merge the four 16-B chunks per line. x-loads KEEP the
// NT hint (read-once streaming is the correct use).
// Frozen from R26: 512-thr / 3 blocks/CU, fp16 pair weights + packed-fp32
// linear (v_pk_fma_f32, op_sel splats), x prefetch rotation, coef fp32 in
// LDS + sorted rolling-coef + sched_barrier(0x7), swizzled b128 staging.
__global__ __launch_bounds__(512)
void main_k(const float* __restrict__ x, const float* __restrict__ cgj,
            const unsigned* __restrict__ wrph, float* __restrict__ out, int B){
  __shared__ float lds[CGF + CJF + XLF];
  float* clg = lds;
  float* clj = lds + CGF;
  float* xl  = lds + CGF + CJF;

  const int tid  = threadIdx.x;
  const int lane = tid & 63;
  const int wv   = tid >> 6;        // 0..7
  const int n    = lane;

  // ---- stage coef tables once per block ----
  for(int idx = tid; idx < CGF + CJF; idx += 512) lds[idx] = cgj[idx];
  __syncthreads();

  const int cgbase = n*PADG;
  const int cjbase = n*PADJ;
  float* xw = xl + wv*1024;        // this wave's 64 i x 16 v staging region
  const int stride = gridDim.x*8;

  // ---- prologue: load + stage first element ----
  int bb = blockIdx.x*8 + wv;
  if(bb < B){
    const f4* src = (const f4*)(x + ((long)bb*64 + lane)*16);
    #pragma unroll
    for(int r=0;r<4;++r){
      f4 a = __builtin_nontemporal_load(src+r);
      int daddr = (lane*16 + r*4) ^ ((lane&7)<<2);
      *(f4*)(xw + daddr) = a;
    }
  }

  for(; bb < B; bb += stride){
    const int nb = bb + stride;

    // ---- issue NEXT element's loads now (HBM latency hides under linear) ----
    f4 xn[4];
    if(nb < B){
      const f4* src = (const f4*)(x + ((long)nb*64 + lane)*16);
      #pragma unroll
      for(int r=0;r<4;++r) xn[r] = __builtin_nontemporal_load(src+r);
    }

    // ---- linear phase (packed): y12[v] = sum_i (w1,w2)[g(v)] * (xv,xv) ----
    f2 y12[16];
    #pragma unroll
    for(int v=0;v<16;++v) y12[v] = (f2)(0.f);

    #pragma unroll 4
    for(int i=0;i<64;++i){
      const unsigned* wp = wrph + i*320 + n;
      unsigned u0 = wp[0], u1 = wp[64], u2 = wp[128], u3 = wp[192], u4 = wp[256];
      f2 w12[5];
      { hf2 h = __builtin_bit_cast(hf2, u0); w12[0][0]=(float)h[0]; w12[0][1]=(float)h[1]; }
      { hf2 h = __builtin_bit_cast(hf2, u1); w12[1][0]=(float)h[0]; w12[1][1]=(float)h[1]; }
      { hf2 h = __builtin_bit_cast(hf2, u2); w12[2][0]=(float)h[0]; w12[2][1]=(float)h[1]; }
      { hf2 h = __builtin_bit_cast(hf2, u3); w12[3][0]=(float)h[0]; w12[3][1]=(float)h[1]; }
      { hf2 h = __builtin_bit_cast(hf2, u4); w12[4][0]=(float)h[0]; w12[4][1]=(float)h[1]; }

      // broadcast reads of x (uniform addr, conflict-free); splats (x_c,x_c)
      // with literal lane indices -> fold into VOP3P op_sel
      #pragma unroll
      for(int g=0;g<4;++g){
        int raddr = (i*16 + g*4) ^ ((i&7)<<2);
        f4 a = *(const f4*)(xw + raddr);
        f2 p0 = __builtin_shufflevector(a, a, 0,0);
        f2 p1 = __builtin_shufflevector(a, a, 1,1);
        f2 p2 = __builtin_shufflevector(a, a, 2,2);
        f2 p3 = __builtin_shufflevector(a, a, 3,3);
        y12[g*4+0] = __builtin_elementwise_fma(w12[GR[g*4+0]], p0, y12[g*4+0]);
        y12[g*4+1] = __builtin_elementwise_fma(w12[GR[g*4+1]], p1, y12[g*4+1]);
        y12[g*4+2] = __builtin_elementwise_fma(w12[GR[g*4+2]], p2, y12[g*4+2]);
        y12[g*4+3] = __builtin_elementwise_fma(w12[GR[g*4+3]], p3, y12[g*4+3]);
      }
    }

    // ---- stage NEXT element into the (now fully-read) buffer ----
    if(nb < B){
      #pragma unroll
      for(int r=0;r<4;++r){
        int daddr = (lane*16 + r*4) ^ ((lane&7)<<2);
        *(f4*)(xw + daddr) = xn[r];
      }
    }

    // ---- bilinear phase: sorted terms, rolling coef register, capped hoist ----
    __builtin_amdgcn_sched_barrier(0x7);
    float acc[16];
    #pragma unroll
    for(int v=0;v<16;++v) acc[v] = y12[v][1];   // + y2

    float c = 0.f;
    #pragma unroll
    for(int q=0;q<NQ;++q){
      if(TAB.qnew[q])
        c = TAB.qgp[q] ? clg[cgbase + TAB.qpath[q]] : clj[cjbase + TAB.qpath[q]];
      float prod = y12[TAB.qj[q]][0] * y12[TAB.qk[q]][1];
      acc[TAB.qi[q]] = fmaf((TAB.qs[q] < 0.f) ? -c : c, prod, acc[TAB.qi[q]]);
      if((q % 24) == 23) __builtin_amdgcn_sched_barrier(0x7);
    }
    __builtin_amdgcn_sched_barrier(0x7);

    // ---- store (PLAIN: let L2 write-combine the 4x16B chunks per line) ----
    {
      f4* op = (f4*)(out + ((long)bb*64 + n)*16);
      #pragma unroll
      for(int r=0;r<4;++r){
        f4 o; o[0]=acc[4*r]; o[1]=acc[4*r+1]; o[2]=acc[4*r+2]; o[3]=acc[4*r+3];
        op[r] = o;
      }
    }
  }
}

extern "C" void kernel_launch(void* const* d_in, const int* in_sizes, int n_in,
                              void* d_out, int out_size, void* d_ws, size_t ws_size,
                              hipStream_t stream){
  const float* x    = (const float*)d_in[0];
  const float* gpw  = (const float*)d_in[1];
  const float* jpw  = (const float*)d_in[2];
  const float* linw = (const float*)d_in[3];
  float* outp = (float*)d_out;

  unsigned* wrph = (unsigned*)d_ws;            // 64*5*64 u32 = 80 KB
  float*    cgj  = (float*)(wrph + 64*5*64);   // CGF+CJF floats (~12.5 KB)

  int B = in_sizes[0] / (64*16);

  prep_wrph<<<80, 256, 0, stream>>>(linw, wrph);
  prep_cpk <<<1,  64,  0, stream>>>(gpw, jpw, cgj);
  main_k   <<<768, 512, 0, stream>>>(x, cgj, wrph, outp, B);
}